// Round 18
// baseline (1106.155 us; speedup 1.0000x reference)
//
#include <hip/hip_runtime.h>
#include <hip/hip_bf16.h>

#define DIN 64
#define DOUT 62
#define ICH 32
#define OCH 64

typedef __bf16 bf16x8 __attribute__((ext_vector_type(8)));
typedef float f32x4 __attribute__((ext_vector_type(4)));
typedef float f32x8 __attribute__((ext_vector_type(8)));
typedef float f32x16 __attribute__((ext_vector_type(16)));

#define AS1U(p) ((const __attribute__((address_space(1))) unsigned int*)(p))
#define AS3U(p) ((__attribute__((address_space(3))) unsigned int*)(p))

// ---------- prep: W -> Wre3 in 32x32x16-fragment-linear order ----------
__global__ void prep_w(const float* __restrict__ W, unsigned short* __restrict__ Wre3) {
    int idx = blockIdx.x * 256 + threadIdx.x;        // 27*2*2*64*8 = 55296
    if (idx >= 27 * OCH * ICH) return;
    int j    = idx & 7;
    int lane = (idx >> 3) & 63;
    int kh   = (idx >> 9) & 1;
    int mt   = (idx >> 10) & 1;
    int tap  = idx >> 11;
    int oc   = mt * 32 + (lane & 31);
    int ic   = kh * 16 + (lane >> 5) * 8 + j;
    float v  = W[((size_t)oc * ICH + ic) * 27 + tap];
    Wre3[idx] = __builtin_bit_cast(unsigned short, (__bf16)v);
}

// ---------- prep: x f32 -> xp bf16, SLICE-MAJOR: xp[b][z][y][s(4)][w(64)][8ic] ----------
__global__ void prep_x(const float* __restrict__ x, unsigned short* __restrict__ xp) {
    int idx = blockIdx.x * 256 + threadIdx.x;        // 2,097,152
    int w = idx & 63;
    int s = (idx >> 6) & 3;
    int y = (idx >> 8) & 63;
    int z = (idx >> 14) & 63;
    int b = idx >> 20;
    const float* xb = x + ((size_t)(b * ICH + s * 8)) * 262144 + (size_t)z * 4096 + y * 64 + w;
    bf16x8 pk;
#pragma unroll
    for (int j = 0; j < 8; ++j)
        pk[j] = (__bf16)xb[(size_t)j * 262144];
    ((int4*)xp)[idx] = __builtin_bit_cast(int4, pk);
}

// ---------- isolation-probe body: KEEP = 0 none / 1 loadA / 2 readB / 3 stage ----------
// Each probe keeps ONE memory stream + the full MFMA/barrier skeleton, x4 repeats.
// Stale regs feed MFMAs (no DCE: acc reduced+stored; LDS sampled).  Writes to out,
// which the real kernel afterwards fully overwrites.
template<int KEEP>
__device__ __forceinline__ void probe_body(
    const unsigned short* __restrict__ Wre3,
    const unsigned short* __restrict__ xp,
    float* __restrict__ out)
{
    __shared__ char xs[2 * 24576 + 256];

    const int tid  = threadIdx.x;
    const int lane = tid & 63;
    const int wave = tid >> 6;

    const int orig = blockIdx.x;
    const int lid  = (orig & 7) * 248 + (orig >> 3);
    const int ht = lid & 15;
    const int rr = lid >> 4;
    const int d  = rr % DOUT;
    const int b  = rr / DOUT;
    const int h0 = ht * 4;

    const int l31 = lane & 31;
    const int lhi = lane >> 5;
    const int row = wave;

    auto stage_chunk = [&](char* buf, int z, int i) {
        int c  = wave * 6 + i;
        int yl = c >> 2;
        int sl = c & 3;
        int srow = h0 + yl; if (srow > 63) srow = 63;
        const unsigned short* src =
            xp + ((((size_t)(b * DIN + z) * DIN + srow) * 4 + sl) * 64) * 8 + lane * 8;
        __builtin_amdgcn_global_load_lds(AS1U(src), AS3U(buf + c * 1024), 16, 0, 0);
    };
    auto loadA = [&](int tap, int4* af) {
        const int4* wp = (const int4*)Wre3 + (size_t)tap * 256 + lane;
#pragma unroll
        for (int q = 0; q < 4; ++q)
            af[q] = wp[q * 64];
    };
    auto readB = [&](const char* buf, int ky, int kx, int4* dst) {
#pragma unroll
        for (int kh = 0; kh < 2; ++kh) {
            const int g = kh * 2 + lhi;
#pragma unroll
            for (int nt = 0; nt < 2; ++nt) {
                int wb = nt * 32 + l31 + kx;
                if (wb > 63) wb = 63;
                dst[kh * 2 + nt] = *(const int4*)(buf + (((row + ky) * 4 + g) * 64 + wb) * 16);
            }
        }
    };

    char* bufA = xs;
    char* bufB = xs + 24576;

#pragma unroll
    for (int i = 0; i < 6; ++i) stage_chunk(bufA, d, i);   // prologue (all probes)
    int4 af[3][4];
    loadA(0, af[0]);
    loadA(1, af[1]);
#pragma unroll
    for (int q = 0; q < 4; ++q) af[2][q] = af[0][q];

    f32x16 acc[2][2];
#pragma unroll
    for (int mt = 0; mt < 2; ++mt)
#pragma unroll
        for (int nt = 0; nt < 2; ++nt)
#pragma unroll
            for (int r = 0; r < 16; ++r) acc[mt][nt][r] = 0.f;

    __syncthreads();

    int4 bfr[2][4];
    readB(bufA, 0, 0, bfr[0]);                       // stale B init (post-barrier)
#pragma unroll
    for (int q = 0; q < 4; ++q) bfr[1][q] = bfr[0][q];

#pragma unroll 1
    for (int rep = 0; rep < 4; ++rep) {              // x4 amplification
#pragma unroll
        for (int kz = 0; kz < 3; ++kz) {
            char* cur = (kz & 1) ? bufB : bufA;
            char* nxt = (kz & 1) ? bufA : bufB;
            if constexpr (KEEP == 2) readB(cur, 0, 0, bfr[0]);

#pragma unroll
            for (int t = 0; t < 9; ++t) {
                const int T = kz * 9 + t;
                if constexpr (KEEP == 1) { if (T < 25) loadA(T + 2, af[(T + 2) % 3]); }
                if constexpr (KEEP == 2) { if (t < 8)  readB(cur, (t + 1) / 3, (t + 1) % 3, bfr[(t + 1) & 1]); }
                if constexpr (KEEP == 3) { if (kz < 2 && t < 6) stage_chunk(nxt, d + kz + 1, t); }

#pragma unroll
                for (int kh = 0; kh < 2; ++kh)
#pragma unroll
                    for (int mt = 0; mt < 2; ++mt)
#pragma unroll
                        for (int nt = 0; nt < 2; ++nt)
                            acc[mt][nt] = __builtin_amdgcn_mfma_f32_32x32x16_bf16(
                                __builtin_bit_cast(bf16x8, af[T % 3][mt * 2 + kh]),
                                __builtin_bit_cast(bf16x8, bfr[t & 1][kh * 2 + nt]),
                                acc[mt][nt], 0, 0, 0);
            }
            if (kz < 2) __syncthreads();
        }
    }

    // keep everything live; real kernel overwrites out afterwards
    float s = 0.f;
#pragma unroll
    for (int mt = 0; mt < 2; ++mt)
#pragma unroll
        for (int nt = 0; nt < 2; ++nt)
#pragma unroll
            for (int r = 0; r < 16; ++r) s += acc[mt][nt][r];
    s += ((const float*)xs)[tid] + ((const float*)(xs + 24576))[tid];
    out[(size_t)orig * 256 + tid] = s;
}

__global__ __launch_bounds__(256, 3) void probe_m(const unsigned short* Wre3, const unsigned short* xp, float* out) { probe_body<0>(Wre3, xp, out); }
__global__ __launch_bounds__(256, 3) void probe_a(const unsigned short* Wre3, const unsigned short* xp, float* out) { probe_body<1>(Wre3, xp, out); }
__global__ __launch_bounds__(256, 3) void probe_b(const unsigned short* Wre3, const unsigned short* xp, float* out) { probe_body<2>(Wre3, xp, out); }
__global__ __launch_bounds__(256, 3) void probe_s(const unsigned short* Wre3, const unsigned short* xp, float* out) { probe_body<3>(Wre3, xp, out); }

// ---------- real kernel: R16 exact (best config, 75.3 us) ----------
__global__ __launch_bounds__(256, 3) void conv3d_mfma_pk(
    const unsigned short* __restrict__ Wre3,
    const unsigned short* __restrict__ xp,
    float* __restrict__ out)
{
    __shared__ char xs[2 * 24576 + 256];

    const int tid  = threadIdx.x;
    const int lane = tid & 63;
    const int wave = tid >> 6;

    const int orig = blockIdx.x;
    const int lid  = (orig & 7) * 248 + (orig >> 3);
    const int ht = lid & 15;
    const int rr = lid >> 4;
    const int d  = rr % DOUT;
    const int b  = rr / DOUT;
    const int h0 = ht * 4;

    const int l31 = lane & 31;
    const int lhi = lane >> 5;
    const int row = wave;

    auto stage_chunk = [&](char* buf, int z, int i) {
        int c  = wave * 6 + i;
        int yl = c >> 2;
        int sl = c & 3;
        int srow = h0 + yl; if (srow > 63) srow = 63;
        const unsigned short* src =
            xp + ((((size_t)(b * DIN + z) * DIN + srow) * 4 + sl) * 64) * 8 + lane * 8;
        __builtin_amdgcn_global_load_lds(AS1U(src), AS3U(buf + c * 1024), 16, 0, 0);
    };
    auto loadA = [&](int tap, int4* af) {
        const int4* wp = (const int4*)Wre3 + (size_t)tap * 256 + lane;
#pragma unroll
        for (int q = 0; q < 4; ++q)
            af[q] = wp[q * 64];
    };
    auto readB = [&](const char* buf, int ky, int kx, int4* dst) {
#pragma unroll
        for (int kh = 0; kh < 2; ++kh) {
            const int g = kh * 2 + lhi;
#pragma unroll
            for (int nt = 0; nt < 2; ++nt) {
                int wb = nt * 32 + l31 + kx;
                if (wb > 63) wb = 63;
                dst[kh * 2 + nt] = *(const int4*)(buf + (((row + ky) * 4 + g) * 64 + wb) * 16);
            }
        }
    };

    char* bufA = xs;
    char* bufB = xs + 24576;

#pragma unroll
    for (int i = 0; i < 6; ++i) stage_chunk(bufA, d, i);
    int4 af[3][4];
    loadA(0, af[0]);
    loadA(1, af[1]);

    f32x16 acc[2][2];
#pragma unroll
    for (int mt = 0; mt < 2; ++mt)
#pragma unroll
        for (int nt = 0; nt < 2; ++nt)
#pragma unroll
            for (int r = 0; r < 16; ++r) acc[mt][nt][r] = 0.f;

    __syncthreads();

    int4 bfr[2][4];
    const bool oddw = (wave & 1) != 0;

#pragma unroll
    for (int kz = 0; kz < 3; ++kz) {
        char* cur = (kz & 1) ? bufB : bufA;
        char* nxt = (kz & 1) ? bufA : bufB;
        readB(cur, 0, 0, bfr[0]);

#pragma unroll
        for (int t = 0; t < 9; ++t) {
            const int T = kz * 9 + t;
            if (oddw) {
                if (t < 8)  readB(cur, (t + 1) / 3, (t + 1) % 3, bfr[(t + 1) & 1]);
                if (T < 25) loadA(T + 2, af[(T + 2) % 3]);
            } else {
                if (T < 25) loadA(T + 2, af[(T + 2) % 3]);
                if (t < 8)  readB(cur, (t + 1) / 3, (t + 1) % 3, bfr[(t + 1) & 1]);
            }
            if (kz < 2 && t < 6) stage_chunk(nxt, d + kz + 1, t);

#pragma unroll
            for (int kh = 0; kh < 2; ++kh)
#pragma unroll
                for (int mt = 0; mt < 2; ++mt)
#pragma unroll
                    for (int nt = 0; nt < 2; ++nt)
                        acc[mt][nt] = __builtin_amdgcn_mfma_f32_32x32x16_bf16(
                            __builtin_bit_cast(bf16x8, af[T % 3][mt * 2 + kh]),
                            __builtin_bit_cast(bf16x8, bfr[t & 1][kh * 2 + nt]),
                            acc[mt][nt], 0, 0, 0);
        }
        if (kz < 2) __syncthreads();
    }

    const int h = h0 + row;
    if (h < DOUT) {
#pragma unroll
        for (int mt = 0; mt < 2; ++mt) {
#pragma unroll
            for (int r = 0; r < 16; ++r) {
                int oc = mt * 32 + (r & 3) + 8 * (r >> 2) + 4 * lhi;
                size_t ob = ((((size_t)b * OCH + oc) * DOUT + d) * DOUT + h) * DOUT;
#pragma unroll
                for (int nt = 0; nt < 2; ++nt) {
                    int ww = nt * 32 + l31;
                    if (ww < DOUT) out[ob + ww] = acc[mt][nt][r];
                }
            }
        }
    }
}

// ---------- fallback (ws too small): reg-staged 16x16 kernel, f32 W direct ----------
__global__ __launch_bounds__(256, 3) void conv3d_mfma_fb(
    const float* __restrict__ x, const float* __restrict__ W,
    float* __restrict__ out)
{
    __shared__ char xs[2][6 * 66 * 64];

    const int tid  = threadIdx.x;
    const int lane = tid & 63;
    const int wave = tid >> 6;

    const int orig = blockIdx.x;
    const int lid  = (orig & 7) * 248 + (orig >> 3);
    const int ht = lid & 15;
    const int rr = lid >> 4;
    const int d  = rr % DOUT;
    const int b  = rr / DOUT;
    const int h0 = ht * 4;

    const int wlo = lane & 15;
    const int whi = lane >> 4;
    const int row = wave;

    const int icg  = wave;
    const int w    = lane;
    const int slot = icg ^ ((w >> 1) & 3);

    auto issueRow = [&](int z, int y) -> f32x8 {
        int gy = h0 + y; if (gy > 63) gy = 63;
        const float* xp2 = x + (((size_t)(b * ICH + icg * 8) * DIN + z) * DIN + gy) * DIN + w;
        f32x8 s;
#pragma unroll
        for (int j = 0; j < 8; ++j) s[j] = xp2[(size_t)j * DIN * DIN * DIN];
        return s;
    };
    auto writeRow = [&](char* buf, int y, f32x8 s) {
        bf16x8 pk;
#pragma unroll
        for (int j = 0; j < 8; ++j) pk[j] = (__bf16)s[j];
        *(int4*)(buf + ((y * 66 + w) * 64 + slot * 16)) = __builtin_bit_cast(int4, pk);
    };
    auto loadA = [&](int tap, int4* af) {
#pragma unroll
        for (int mt = 0; mt < 4; ++mt) {
            const float* wp = W + ((size_t)(mt * 16 + wlo) * ICH + whi * 8) * 27 + tap;
            bf16x8 t;
#pragma unroll
            for (int j = 0; j < 8; ++j) t[j] = (__bf16)wp[j * 27];
            af[mt] = __builtin_bit_cast(int4, t);
        }
    };
    auto readB = [&](const char* buf, int ky, int kx, int4* dst) {
#pragma unroll
        for (int nt = 0; nt < 4; ++nt) {
            int wb = nt * 16 + wlo + kx;
            int sl = whi ^ ((wb >> 1) & 3);
            dst[nt] = *(const int4*)(buf + (((row + ky) * 66 + wb) * 64 + sl * 16));
        }
    };

    if (tid < 96) {
        int bu = tid / 48, q2 = tid % 48;
        int y = q2 >> 3, q = q2 & 7;
        int w2 = 64 + (q >> 2), sl = q & 3;
        *(int4*)(xs[bu] + ((y * 66 + w2) * 64 + sl * 16)) = int4{0, 0, 0, 0};
    }
    {
        f32x8 s0 = issueRow(d, 0), s1 = issueRow(d, 1), s2 = issueRow(d, 2);
        writeRow(xs[0], 0, s0); s0 = issueRow(d, 3);
        writeRow(xs[0], 1, s1); s1 = issueRow(d, 4);
        writeRow(xs[0], 2, s2); s2 = issueRow(d, 5);
        writeRow(xs[0], 3, s0); writeRow(xs[0], 4, s1); writeRow(xs[0], 5, s2);
    }
    int4 af[2][4];
    loadA(0, af[0]);
    __syncthreads();

    f32x4 acc[4][4];
#pragma unroll
    for (int mt = 0; mt < 4; ++mt)
#pragma unroll
        for (int nt = 0; nt < 4; ++nt)
            acc[mt][nt] = f32x4{0.f, 0.f, 0.f, 0.f};

    int4 bfr[2][4];

#pragma unroll
    for (int kz = 0; kz < 3; ++kz) {
        char* cur = xs[kz & 1];
        char* nxt = xs[(kz + 1) & 1];
        f32x8 s0, s1, s2;
        readB(cur, 0, 0, bfr[0]);
#pragma unroll
        for (int t = 0; t < 9; ++t) {
            const int T = kz * 9 + t;
            if (T < 26) loadA(T + 1, af[(T + 1) & 1]);
            if (t < 8)  readB(cur, (t + 1) / 3, (t + 1) % 3, bfr[(t + 1) & 1]);
            if (kz < 2) {
                if (t == 3) writeRow(nxt, 0, s0);
                if (t == 4) writeRow(nxt, 1, s1);
                if (t == 5) writeRow(nxt, 2, s2);
                if (t == 6) writeRow(nxt, 3, s0);
                if (t == 7) writeRow(nxt, 4, s1);
                if (t == 8) writeRow(nxt, 5, s2);
                if (t == 0) s0 = issueRow(d + kz + 1, 0);
                if (t == 1) s1 = issueRow(d + kz + 1, 1);
                if (t == 2) s2 = issueRow(d + kz + 1, 2);
                if (t == 3) s0 = issueRow(d + kz + 1, 3);
                if (t == 4) s1 = issueRow(d + kz + 1, 4);
                if (t == 5) s2 = issueRow(d + kz + 1, 5);
            }
#pragma unroll
            for (int mt = 0; mt < 4; ++mt)
#pragma unroll
                for (int nt = 0; nt < 4; ++nt)
                    acc[mt][nt] = __builtin_amdgcn_mfma_f32_16x16x32_bf16(
                        __builtin_bit_cast(bf16x8, af[T & 1][mt]),
                        __builtin_bit_cast(bf16x8, bfr[t & 1][nt]),
                        acc[mt][nt], 0, 0, 0);
        }
        if (kz < 2) __syncthreads();
    }

    const int h = h0 + row;
    if (h < DOUT) {
#pragma unroll
        for (int mt = 0; mt < 4; ++mt) {
#pragma unroll
            for (int r = 0; r < 4; ++r) {
                int oc = mt * 16 + whi * 4 + r;
                size_t ob = ((((size_t)b * OCH + oc) * DOUT + d) * DOUT + h) * DOUT;
#pragma unroll
                for (int nt = 0; nt < 4; ++nt) {
                    int ww = nt * 16 + wlo;
                    if (ww < DOUT) out[ob + ww] = acc[mt][nt][r];
                }
            }
        }
    }
}

extern "C" void kernel_launch(void* const* d_in, const int* in_sizes, int n_in,
                              void* d_out, int out_size, void* d_ws, size_t ws_size,
                              hipStream_t stream) {
    const float* x = (const float*)d_in[0];
    const float* W = (const float*)d_in[1];
    float* out = (float*)d_out;

    const size_t wre_elems = (size_t)27 * OCH * ICH;
    const size_t xp_elems  = (size_t)2 * DIN * DIN * DIN * ICH;
    const size_t need = (wre_elems + xp_elems) * 2 + 256;
    const dim3 grid(2 * DOUT * 16);                  // 1984 = 8*248

    if (ws_size >= need) {
        unsigned short* Wre3 = (unsigned short*)d_ws;
        unsigned short* xp   = Wre3 + wre_elems;
        prep_w<<<216, 256, 0, stream>>>(W, Wre3);
        prep_x<<<8192, 256, 0, stream>>>(x, xp);
        // --- isolation probes, x4 amplified, distinct names (read dur from rocprof) ---
        probe_m<<<grid, 256, 0, stream>>>(Wre3, xp, out);   // MFMA + barriers only
        probe_a<<<grid, 256, 0, stream>>>(Wre3, xp, out);   // + loadA stream
        probe_b<<<grid, 256, 0, stream>>>(Wre3, xp, out);   // + readB stream
        probe_s<<<grid, 256, 0, stream>>>(Wre3, xp, out);   // + staging stream
        // --- real kernel (R16 exact; fully overwrites out) ---
        conv3d_mfma_pk<<<grid, 256, 0, stream>>>(Wre3, xp, out);
    } else {
        conv3d_mfma_fb<<<grid, 256, 0, stream>>>(x, W, out);
    }
}

// Round 19
// 87.173 us; speedup vs baseline: 12.6893x; 12.6893x over previous
//
#include <hip/hip_runtime.h>
#include <hip/hip_bf16.h>

#define DIN 64
#define DOUT 62
#define ICH 32
#define OCH 64

typedef __bf16 bf16x8 __attribute__((ext_vector_type(8)));
typedef float f32x4 __attribute__((ext_vector_type(4)));
typedef float f32x8 __attribute__((ext_vector_type(8)));
typedef float f32x16 __attribute__((ext_vector_type(16)));

#define AS1U(p) ((const __attribute__((address_space(1))) unsigned int*)(p))
#define AS3U(p) ((__attribute__((address_space(3))) unsigned int*)(p))

// ---------- prep: W -> Wre3 in 32x32x16-fragment-linear order ----------
// Wre3[(((tap*2+mt)*2+kh)*64+lane)*8+j] = bf16( W[oc=mt*32+(lane&31)][ic=kh*16+(lane>>5)*8+j][tap] )
__global__ void prep_w(const float* __restrict__ W, unsigned short* __restrict__ Wre3) {
    int idx = blockIdx.x * 256 + threadIdx.x;        // 55296
    if (idx >= 27 * OCH * ICH) return;
    int j    = idx & 7;
    int lane = (idx >> 3) & 63;
    int kh   = (idx >> 9) & 1;
    int mt   = (idx >> 10) & 1;
    int tap  = idx >> 11;
    int oc   = mt * 32 + (lane & 31);
    int ic   = kh * 16 + (lane >> 5) * 8 + j;
    float v  = W[((size_t)oc * ICH + ic) * 27 + tap];
    Wre3[idx] = __builtin_bit_cast(unsigned short, (__bf16)v);
}

// ---------- prep: x f32 -> xp bf16, SLICE-MAJOR: xp[b][z][y][s(4)][w(64)][8ic] ----------
__global__ void prep_x(const float* __restrict__ x, unsigned short* __restrict__ xp) {
    int idx = blockIdx.x * 256 + threadIdx.x;        // 2,097,152
    int w = idx & 63;
    int s = (idx >> 6) & 3;
    int y = (idx >> 8) & 63;
    int z = (idx >> 14) & 63;
    int b = idx >> 20;
    const float* xb = x + ((size_t)(b * ICH + s * 8)) * 262144 + (size_t)z * 4096 + y * 64 + w;
    bf16x8 pk;
#pragma unroll
    for (int j = 0; j < 8; ++j)
        pk[j] = (__bf16)xb[(size_t)j * 262144];
    ((int4*)xp)[idx] = __builtin_bit_cast(int4, pk);
}

// ---------- main: implicit GEMM, 32x32x16, wave = 64oc x 128 (2 h-rows) ----------
// Halves A-bytes/FLOP (the measured L1-BW wall).  Block = (b,d,8 h-rows) x 64oc x 64w,
// 4 waves, 2 rows/wave.  LDS plane 40KB [y(10)][s(4)][w(64)][16B] x2 = 80KB -> 2 blocks/CU.
// 256 unified regs/wave: acc 128 AGPR + af-dbuf 32 + bfr 32 + addr.
__global__ __launch_bounds__(256, 2) void conv3d_mfma_pk(
    const unsigned short* __restrict__ Wre3,
    const unsigned short* __restrict__ xp,
    float* __restrict__ out)
{
    __shared__ char xs[2][40960];                    // 81,920 B -> 2 blocks/CU

    const int tid  = threadIdx.x;
    const int lane = tid & 63;
    const int wave = tid >> 6;                       // 0..3, owns rows 2w,2w+1

    // bijective XCD-aware swizzle (nwg = 992 = 8*124 exactly)
    const int orig = blockIdx.x;
    const int lid  = (orig & 7) * 124 + (orig >> 3);
    const int ht = lid & 7;
    const int rr = lid >> 3;                         // 0..123
    const int d  = rr % DOUT;
    const int b  = rr / DOUT;
    const int h0 = ht * 8;

    const int l31 = lane & 31;                       // w-in-tile / oc-in-tile
    const int lhi = lane >> 5;                       // k-subgroup (8 ic) within k-half
    const int row0 = wave * 2;                       // first of the wave's 2 h-rows

    // one 1KB chunk (c = y*4+s) of a plane: one global_load_lds_dwordx4, linear dest
    auto stage_chunk = [&](char* buf, int z, int i) {
        int c  = wave * 10 + i;                      // 0..39
        int yl = c >> 2;                             // y row 0..9
        int sl = c & 3;                              // ic-slice
        int srow = h0 + yl; if (srow > 63) srow = 63;   // clamped rows feed only discarded h
        const unsigned short* src =
            xp + ((((size_t)(b * DIN + z) * DIN + srow) * 4 + sl) * 64) * 8 + lane * 8;
        __builtin_amdgcn_global_load_lds(AS1U(src), AS3U(buf + c * 1024), 16, 0, 0);
    };
    auto loadA = [&](int tap, int4* af) {            // 4 coalesced dwordx4 (tap stride 256 int4)
        const int4* wp = (const int4*)Wre3 + (size_t)tap * 256 + lane;
#pragma unroll
        for (int q = 0; q < 4; ++q)
            af[q] = wp[q * 64];
    };
    // B for one h-row: dst[kh*2+nt], 4 x ds_read_b128, conflict-free (contiguous 512B runs)
    auto readB = [&](const char* buf, int yloc, int kx, int4* dst) {
#pragma unroll
        for (int kh = 0; kh < 2; ++kh) {
            const int g = kh * 2 + lhi;
#pragma unroll
            for (int nt = 0; nt < 2; ++nt) {
                int wb = nt * 32 + l31 + kx;
                if (wb > 63) wb = 63;                // cols 62/63 only (discarded outputs)
                dst[kh * 2 + nt] = *(const int4*)(buf + ((yloc * 4 + g) * 64 + wb) * 16);
            }
        }
    };

#pragma unroll
    for (int i = 0; i < 10; ++i) stage_chunk(xs[0], d, i);   // plane kz=0 (burst, once)
    int4 af[2][4];
    loadA(0, af[0]);

    f32x16 acc[2][2][2];                             // [row][mt][nt]
#pragma unroll
    for (int r2 = 0; r2 < 2; ++r2)
#pragma unroll
        for (int mt = 0; mt < 2; ++mt)
#pragma unroll
            for (int nt = 0; nt < 2; ++nt)
#pragma unroll
                for (int r = 0; r < 16; ++r) acc[r2][mt][nt][r] = 0.f;

    __syncthreads();                                 // plane 0 ready

    int4 bfr0[4], bfr1[4];

#pragma unroll                                        // kz static -> all indices compile-time
    for (int kz = 0; kz < 3; ++kz) {
        char* cur = xs[kz & 1];
        char* nxt = xs[(kz + 1) & 1];

#pragma unroll
        for (int t = 0; t < 9; ++t) {
            const int T  = kz * 9 + t;
            const int ky = t / 3, kx = t % 3;

            readB(cur, row0 + ky, kx, bfr0);         // row 0's B
            if (T < 26) loadA(T + 1, af[(T + 1) & 1]);       // A: 1-deep (L1)
            // staging interleave: 10 chunks over 9 taps (2 at t=0), after loadA (vmcnt order)
            if (kz < 2) {
                if (t == 0) { stage_chunk(nxt, d + kz + 1, 0); stage_chunk(nxt, d + kz + 1, 1); }
                else        { stage_chunk(nxt, d + kz + 1, t + 1); }
            }
            readB(cur, row0 + 1 + ky, kx, bfr1);     // row 1's B (overlaps row 0's MFMAs)

#pragma unroll
            for (int kh = 0; kh < 2; ++kh)           // row 0: acc chain distance 4
#pragma unroll
                for (int mt = 0; mt < 2; ++mt)
#pragma unroll
                    for (int nt = 0; nt < 2; ++nt)
                        acc[0][mt][nt] = __builtin_amdgcn_mfma_f32_32x32x16_bf16(
                            __builtin_bit_cast(bf16x8, af[T & 1][mt * 2 + kh]),
                            __builtin_bit_cast(bf16x8, bfr0[kh * 2 + nt]),
                            acc[0][mt][nt], 0, 0, 0);
#pragma unroll
            for (int kh = 0; kh < 2; ++kh)           // row 1
#pragma unroll
                for (int mt = 0; mt < 2; ++mt)
#pragma unroll
                    for (int nt = 0; nt < 2; ++nt)
                        acc[1][mt][nt] = __builtin_amdgcn_mfma_f32_32x32x16_bf16(
                            __builtin_bit_cast(bf16x8, af[T & 1][mt * 2 + kh]),
                            __builtin_bit_cast(bf16x8, bfr1[kh * 2 + nt]),
                            acc[1][mt][nt], 0, 0, 0);
        }
        if (kz < 2) __syncthreads();                 // next plane landed; cur free
    }

    // ---- store: D col=lane&31 -> w, row=(r&3)+8*(r>>2)+4*(lane>>5) -> oc ----
#pragma unroll
    for (int r2 = 0; r2 < 2; ++r2) {
        const int h = h0 + row0 + r2;
        if (h < DOUT) {
#pragma unroll
            for (int mt = 0; mt < 2; ++mt) {
#pragma unroll
                for (int r = 0; r < 16; ++r) {
                    int oc = mt * 32 + (r & 3) + 8 * (r >> 2) + 4 * lhi;
                    size_t ob = ((((size_t)b * OCH + oc) * DOUT + d) * DOUT + h) * DOUT;
#pragma unroll
                    for (int nt = 0; nt < 2; ++nt) {
                        int ww = nt * 32 + l31;
                        if (ww < DOUT) out[ob + ww] = acc[r2][mt][nt][r];
                    }
                }
            }
        }
    }
}

// ---------- fallback (ws too small): reg-staged 16x16 kernel, f32 W direct ----------
__global__ __launch_bounds__(256, 3) void conv3d_mfma_fb(
    const float* __restrict__ x, const float* __restrict__ W,
    float* __restrict__ out)
{
    __shared__ char xs[2][6 * 66 * 64];

    const int tid  = threadIdx.x;
    const int lane = tid & 63;
    const int wave = tid >> 6;

    const int orig = blockIdx.x;
    const int lid  = (orig & 7) * 248 + (orig >> 3);
    const int ht = lid & 15;
    const int rr = lid >> 4;
    const int d  = rr % DOUT;
    const int b  = rr / DOUT;
    const int h0 = ht * 4;

    const int wlo = lane & 15;
    const int whi = lane >> 4;
    const int row = wave;

    const int icg  = wave;
    const int w    = lane;
    const int slot = icg ^ ((w >> 1) & 3);

    auto issueRow = [&](int z, int y) -> f32x8 {
        int gy = h0 + y; if (gy > 63) gy = 63;
        const float* xp2 = x + (((size_t)(b * ICH + icg * 8) * DIN + z) * DIN + gy) * DIN + w;
        f32x8 s;
#pragma unroll
        for (int j = 0; j < 8; ++j) s[j] = xp2[(size_t)j * DIN * DIN * DIN];
        return s;
    };
    auto writeRow = [&](char* buf, int y, f32x8 s) {
        bf16x8 pk;
#pragma unroll
        for (int j = 0; j < 8; ++j) pk[j] = (__bf16)s[j];
        *(int4*)(buf + ((y * 66 + w) * 64 + slot * 16)) = __builtin_bit_cast(int4, pk);
    };
    auto loadA = [&](int tap, int4* af) {
#pragma unroll
        for (int mt = 0; mt < 4; ++mt) {
            const float* wp = W + ((size_t)(mt * 16 + wlo) * ICH + whi * 8) * 27 + tap;
            bf16x8 t;
#pragma unroll
            for (int j = 0; j < 8; ++j) t[j] = (__bf16)wp[j * 27];
            af[mt] = __builtin_bit_cast(int4, t);
        }
    };
    auto readB = [&](const char* buf, int ky, int kx, int4* dst) {
#pragma unroll
        for (int nt = 0; nt < 4; ++nt) {
            int wb = nt * 16 + wlo + kx;
            int sl = whi ^ ((wb >> 1) & 3);
            dst[nt] = *(const int4*)(buf + (((row + ky) * 66 + wb) * 64 + sl * 16));
        }
    };

    if (tid < 96) {
        int bu = tid / 48, q2 = tid % 48;
        int y = q2 >> 3, q = q2 & 7;
        int w2 = 64 + (q >> 2), sl = q & 3;
        *(int4*)(xs[bu] + ((y * 66 + w2) * 64 + sl * 16)) = int4{0, 0, 0, 0};
    }
    {
        f32x8 s0 = issueRow(d, 0), s1 = issueRow(d, 1), s2 = issueRow(d, 2);
        writeRow(xs[0], 0, s0); s0 = issueRow(d, 3);
        writeRow(xs[0], 1, s1); s1 = issueRow(d, 4);
        writeRow(xs[0], 2, s2); s2 = issueRow(d, 5);
        writeRow(xs[0], 3, s0); writeRow(xs[0], 4, s1); writeRow(xs[0], 5, s2);
    }
    int4 af[2][4];
    loadA(0, af[0]);
    __syncthreads();

    f32x4 acc[4][4];
#pragma unroll
    for (int mt = 0; mt < 4; ++mt)
#pragma unroll
        for (int nt = 0; nt < 4; ++nt)
            acc[mt][nt] = f32x4{0.f, 0.f, 0.f, 0.f};

    int4 bfr[2][4];

#pragma unroll
    for (int kz = 0; kz < 3; ++kz) {
        char* cur = xs[kz & 1];
        char* nxt = xs[(kz + 1) & 1];
        f32x8 s0, s1, s2;
        readB(cur, 0, 0, bfr[0]);
#pragma unroll
        for (int t = 0; t < 9; ++t) {
            const int T = kz * 9 + t;
            if (T < 26) loadA(T + 1, af[(T + 1) & 1]);
            if (t < 8)  readB(cur, (t + 1) / 3, (t + 1) % 3, bfr[(t + 1) & 1]);
            if (kz < 2) {
                if (t == 3) writeRow(nxt, 0, s0);
                if (t == 4) writeRow(nxt, 1, s1);
                if (t == 5) writeRow(nxt, 2, s2);
                if (t == 6) writeRow(nxt, 3, s0);
                if (t == 7) writeRow(nxt, 4, s1);
                if (t == 8) writeRow(nxt, 5, s2);
                if (t == 0) s0 = issueRow(d + kz + 1, 0);
                if (t == 1) s1 = issueRow(d + kz + 1, 1);
                if (t == 2) s2 = issueRow(d + kz + 1, 2);
                if (t == 3) s0 = issueRow(d + kz + 1, 3);
                if (t == 4) s1 = issueRow(d + kz + 1, 4);
                if (t == 5) s2 = issueRow(d + kz + 1, 5);
            }
#pragma unroll
            for (int mt = 0; mt < 4; ++mt)
#pragma unroll
                for (int nt = 0; nt < 4; ++nt)
                    acc[mt][nt] = __builtin_amdgcn_mfma_f32_16x16x32_bf16(
                        __builtin_bit_cast(bf16x8, af[T & 1][mt]),
                        __builtin_bit_cast(bf16x8, bfr[t & 1][nt]),
                        acc[mt][nt], 0, 0, 0);
        }
        if (kz < 2) __syncthreads();
    }

    const int h = h0 + row;
    if (h < DOUT) {
#pragma unroll
        for (int mt = 0; mt < 4; ++mt) {
#pragma unroll
            for (int r = 0; r < 4; ++r) {
                int oc = mt * 16 + whi * 4 + r;
                size_t ob = ((((size_t)b * OCH + oc) * DOUT + d) * DOUT + h) * DOUT;
#pragma unroll
                for (int nt = 0; nt < 4; ++nt) {
                    int ww = nt * 16 + wlo;
                    if (ww < DOUT) out[ob + ww] = acc[mt][nt][r];
                }
            }
        }
    }
}

extern "C" void kernel_launch(void* const* d_in, const int* in_sizes, int n_in,
                              void* d_out, int out_size, void* d_ws, size_t ws_size,
                              hipStream_t stream) {
    const float* x = (const float*)d_in[0];
    const float* W = (const float*)d_in[1];
    float* out = (float*)d_out;

    const size_t wre_elems = (size_t)27 * OCH * ICH;             // 55,296 ushort
    const size_t xp_elems  = (size_t)2 * DIN * DIN * DIN * ICH;  // 16,777,216 ushort
    const size_t need = (wre_elems + xp_elems) * 2 + 256;

    if (ws_size >= need) {
        unsigned short* Wre3 = (unsigned short*)d_ws;
        unsigned short* xp   = Wre3 + wre_elems;
        prep_w<<<216, 256, 0, stream>>>(W, Wre3);
        prep_x<<<8192, 256, 0, stream>>>(x, xp);
        conv3d_mfma_pk<<<dim3(2 * DOUT * 8), 256, 0, stream>>>(Wre3, xp, out);  // 992 = 8*124
    } else {
        conv3d_mfma_fb<<<dim3(2 * DOUT * 16), 256, 0, stream>>>(x, W, out);
    }
}

// Round 21
// 84.688 us; speedup vs baseline: 13.0615x; 1.0293x over previous
//
#include <hip/hip_runtime.h>
#include <hip/hip_bf16.h>

#define DIN 64
#define DOUT 62
#define ICH 32
#define OCH 64

typedef __bf16 bf16x8 __attribute__((ext_vector_type(8)));
typedef float f32x4 __attribute__((ext_vector_type(4)));
typedef float f32x8 __attribute__((ext_vector_type(8)));
typedef float f32x16 __attribute__((ext_vector_type(16)));

#define AS1U(p) ((const __attribute__((address_space(1))) unsigned int*)(p))
#define AS3U(p) ((__attribute__((address_space(3))) unsigned int*)(p))

// ---------- merged prep: one launch does both W and x repack (disjoint writes) ----------
// Wre3[(((tap*2+mt)*2+kh)*64+lane)*8+j] = bf16( W[oc=mt*32+(lane&31)][ic=kh*16+(lane>>5)*8+j][tap] )
// xp SLICE-MAJOR: xp[b][z][y][s(4)][w(64)][8ic] bf16 (16B packets, fragment-linear).
__global__ void prep_all(const float* __restrict__ x, const float* __restrict__ W,
                         unsigned short* __restrict__ Wre3, unsigned short* __restrict__ xp) {
    const int bid = blockIdx.x;
    if (bid < 8192) {
        // ---- prep_x body (verified R12..R18) ----
        int idx = bid * 256 + threadIdx.x;           // 2,097,152 packets
        int w = idx & 63;
        int s = (idx >> 6) & 3;
        int y = (idx >> 8) & 63;
        int z = (idx >> 14) & 63;
        int b = idx >> 20;
        const float* xb = x + ((size_t)(b * ICH + s * 8)) * 262144 + (size_t)z * 4096 + y * 64 + w;
        bf16x8 pk;
#pragma unroll
        for (int j = 0; j < 8; ++j)
            pk[j] = (__bf16)xb[(size_t)j * 262144];
        ((int4*)xp)[idx] = __builtin_bit_cast(int4, pk);
    } else {
        // ---- prep_w body (verified R10..R18) ----
        int idx = (bid - 8192) * 256 + threadIdx.x;  // 55,296 elements
        if (idx < 27 * OCH * ICH) {
            int j    = idx & 7;
            int lane = (idx >> 3) & 63;
            int kh   = (idx >> 9) & 1;
            int mt   = (idx >> 10) & 1;
            int tap  = idx >> 11;
            int oc   = mt * 32 + (lane & 31);
            int ic   = kh * 16 + (lane >> 5) * 8 + j;
            float v  = W[((size_t)oc * ICH + ic) * 27 + tap];
            Wre3[idx] = __builtin_bit_cast(unsigned short, (__bf16)v);
        }
    }
}

// ---------- main: R16 exact (replay-verified 3 rounds; main ~75.3 us) ----------
// implicit GEMM, 32x32x16 MFMA; block tile (b, d, 4 h-rows) x 64 oc x 64 w; wave = one h row.
// LDS 2 x 24KB planes [y(6)][s(4)][w(64)][16B], linear copy from fragment-linear xp.
// A 2-deep prefetch (coalesced, tap stride 256 int4); B 1-deep from LDS (conflict-free);
// staging interleaved one chunk/wave/tap AFTER loadA (in-order vmcnt discipline).
__global__ __launch_bounds__(256, 3) void conv3d_mfma_pk(
    const unsigned short* __restrict__ Wre3,
    const unsigned short* __restrict__ xp,
    float* __restrict__ out)
{
    __shared__ char xs[2 * 24576 + 256];             // 2 plane bufs + guard

    const int tid  = threadIdx.x;
    const int lane = tid & 63;
    const int wave = tid >> 6;

    // bijective XCD-aware swizzle (nwg = 1984 = 8*248 exactly)
    const int orig = blockIdx.x;
    const int lid  = (orig & 7) * 248 + (orig >> 3);
    const int ht = lid & 15;
    const int rr = lid >> 4;
    const int d  = rr % DOUT;
    const int b  = rr / DOUT;
    const int h0 = ht * 4;

    const int l31 = lane & 31;                       // w-in-tile / oc-in-tile
    const int lhi = lane >> 5;                       // k-subgroup (8 ic) within k-half
    const int row = wave;                            // h row

    auto stage_chunk = [&](char* buf, int z, int i) {
        int c  = wave * 6 + i;                       // 0..23
        int yl = c >> 2;                             // y row 0..5
        int sl = c & 3;                              // ic-slice
        int srow = h0 + yl; if (srow > 63) srow = 63;   // clamped rows feed only discarded h
        const unsigned short* src =
            xp + ((((size_t)(b * DIN + z) * DIN + srow) * 4 + sl) * 64) * 8 + lane * 8;
        __builtin_amdgcn_global_load_lds(AS1U(src), AS3U(buf + c * 1024), 16, 0, 0);
    };
    auto loadA = [&](int tap, int4* af) {            // 4 coalesced dwordx4 (tap stride 256 int4)
        const int4* wp = (const int4*)Wre3 + (size_t)tap * 256 + lane;
#pragma unroll
        for (int q = 0; q < 4; ++q)
            af[q] = wp[q * 64];
    };
    auto readB = [&](const char* buf, int ky, int kx, int4* dst) {   // 4 x ds_read_b128
#pragma unroll
        for (int kh = 0; kh < 2; ++kh) {
            const int g = kh * 2 + lhi;
#pragma unroll
            for (int nt = 0; nt < 2; ++nt) {
                int wb = nt * 32 + l31 + kx;
                if (wb > 63) wb = 63;                // cols 62/63 only (discarded outputs)
                dst[kh * 2 + nt] = *(const int4*)(buf + (((row + ky) * 4 + g) * 64 + wb) * 16);
            }
        }
    };

    char* bufA = xs;
    char* bufB = xs + 24576;

#pragma unroll
    for (int i = 0; i < 6; ++i) stage_chunk(bufA, d, i);   // plane kz=0 (burst, once)
    int4 af[3][4];
    loadA(0, af[0]);
    loadA(1, af[1]);

    f32x16 acc[2][2];
#pragma unroll
    for (int mt = 0; mt < 2; ++mt)
#pragma unroll
        for (int nt = 0; nt < 2; ++nt)
#pragma unroll
            for (int r = 0; r < 16; ++r) acc[mt][nt][r] = 0.f;

    __syncthreads();                                 // plane 0 ready

    int4 bfr[2][4];
    const bool oddw = (wave & 1) != 0;               // wave-uniform branch

#pragma unroll                                        // kz static -> all indices compile-time
    for (int kz = 0; kz < 3; ++kz) {
        char* cur = (kz & 1) ? bufB : bufA;
        char* nxt = (kz & 1) ? bufA : bufB;
        readB(cur, 0, 0, bfr[0]);                    // per-segment B prologue

#pragma unroll
        for (int t = 0; t < 9; ++t) {
            const int T = kz * 9 + t;
            // de-phased issue: even waves A-then-B, odd waves B-then-A
            if (oddw) {
                if (t < 8)  readB(cur, (t + 1) / 3, (t + 1) % 3, bfr[(t + 1) & 1]);
                if (T < 25) loadA(T + 2, af[(T + 2) % 3]);
            } else {
                if (T < 25) loadA(T + 2, af[(T + 2) % 3]);
                if (t < 8)  readB(cur, (t + 1) / 3, (t + 1) % 3, bfr[(t + 1) & 1]);
            }
            if (kz < 2 && t < 6) stage_chunk(nxt, d + kz + 1, t);   // after loads (vmcnt order)

#pragma unroll
            for (int kh = 0; kh < 2; ++kh)           // kh-outer: acc chain distance = 4
#pragma unroll
                for (int mt = 0; mt < 2; ++mt)
#pragma unroll
                    for (int nt = 0; nt < 2; ++nt)
                        acc[mt][nt] = __builtin_amdgcn_mfma_f32_32x32x16_bf16(
                            __builtin_bit_cast(bf16x8, af[T % 3][mt * 2 + kh]),
                            __builtin_bit_cast(bf16x8, bfr[t & 1][kh * 2 + nt]),
                            acc[mt][nt], 0, 0, 0);
        }
        if (kz < 2) __syncthreads();                 // next plane landed; cur free
    }

    // ---- store: D col=lane&31 -> w, row=(r&3)+8*(r>>2)+4*(lane>>5) -> oc ----
    const int h = h0 + row;
    if (h < DOUT) {
#pragma unroll
        for (int mt = 0; mt < 2; ++mt) {
#pragma unroll
            for (int r = 0; r < 16; ++r) {
                int oc = mt * 32 + (r & 3) + 8 * (r >> 2) + 4 * lhi;
                size_t ob = ((((size_t)b * OCH + oc) * DOUT + d) * DOUT + h) * DOUT;
#pragma unroll
                for (int nt = 0; nt < 2; ++nt) {
                    int ww = nt * 32 + l31;
                    if (ww < DOUT) out[ob + ww] = acc[mt][nt][r];
                }
            }
        }
    }
}

// ---------- fallback (ws too small): reg-staged 16x16 kernel, f32 W direct ----------
__global__ __launch_bounds__(256, 3) void conv3d_mfma_fb(
    const float* __restrict__ x, const float* __restrict__ W,
    float* __restrict__ out)
{
    __shared__ char xs[2][6 * 66 * 64];

    const int tid  = threadIdx.x;
    const int lane = tid & 63;
    const int wave = tid >> 6;

    const int orig = blockIdx.x;
    const int lid  = (orig & 7) * 248 + (orig >> 3);
    const int ht = lid & 15;
    const int rr = lid >> 4;
    const int d  = rr % DOUT;
    const int b  = rr / DOUT;
    const int h0 = ht * 4;

    const int wlo = lane & 15;
    const int whi = lane >> 4;
    const int row = wave;

    const int icg  = wave;
    const int w    = lane;
    const int slot = icg ^ ((w >> 1) & 3);

    auto issueRow = [&](int z, int y) -> f32x8 {
        int gy = h0 + y; if (gy > 63) gy = 63;
        const float* xp2 = x + (((size_t)(b * ICH + icg * 8) * DIN + z) * DIN + gy) * DIN + w;
        f32x8 s;
#pragma unroll
        for (int j = 0; j < 8; ++j) s[j] = xp2[(size_t)j * DIN * DIN * DIN];
        return s;
    };
    auto writeRow = [&](char* buf, int y, f32x8 s) {
        bf16x8 pk;
#pragma unroll
        for (int j = 0; j < 8; ++j) pk[j] = (__bf16)s[j];
        *(int4*)(buf + ((y * 66 + w) * 64 + slot * 16)) = __builtin_bit_cast(int4, pk);
    };
    auto loadA = [&](int tap, int4* af) {
#pragma unroll
        for (int mt = 0; mt < 4; ++mt) {
            const float* wp = W + ((size_t)(mt * 16 + wlo) * ICH + whi * 8) * 27 + tap;
            bf16x8 t;
#pragma unroll
            for (int j = 0; j < 8; ++j) t[j] = (__bf16)wp[j * 27];
            af[mt] = __builtin_bit_cast(int4, t);
        }
    };
    auto readB = [&](const char* buf, int ky, int kx, int4* dst) {
#pragma unroll
        for (int nt = 0; nt < 4; ++nt) {
            int wb = nt * 16 + wlo + kx;
            int sl = whi ^ ((wb >> 1) & 3);
            dst[nt] = *(const int4*)(buf + (((row + ky) * 66 + wb) * 64 + sl * 16));
        }
    };

    if (tid < 96) {
        int bu = tid / 48, q2 = tid % 48;
        int y = q2 >> 3, q = q2 & 7;
        int w2 = 64 + (q >> 2), sl = q & 3;
        *(int4*)(xs[bu] + ((y * 66 + w2) * 64 + sl * 16)) = int4{0, 0, 0, 0};
    }
    {
        f32x8 s0 = issueRow(d, 0), s1 = issueRow(d, 1), s2 = issueRow(d, 2);
        writeRow(xs[0], 0, s0); s0 = issueRow(d, 3);
        writeRow(xs[0], 1, s1); s1 = issueRow(d, 4);
        writeRow(xs[0], 2, s2); s2 = issueRow(d, 5);
        writeRow(xs[0], 3, s0); writeRow(xs[0], 4, s1); writeRow(xs[0], 5, s2);
    }
    int4 af[2][4];
    loadA(0, af[0]);
    __syncthreads();

    f32x4 acc[4][4];
#pragma unroll
    for (int mt = 0; mt < 4; ++mt)
#pragma unroll
        for (int nt = 0; nt < 4; ++nt)
            acc[mt][nt] = f32x4{0.f, 0.f, 0.f, 0.f};

    int4 bfr[2][4];

#pragma unroll
    for (int kz = 0; kz < 3; ++kz) {
        char* cur = xs[kz & 1];
        char* nxt = xs[(kz + 1) & 1];
        f32x8 s0, s1, s2;
        readB(cur, 0, 0, bfr[0]);
#pragma unroll
        for (int t = 0; t < 9; ++t) {
            const int T = kz * 9 + t;
            if (T < 26) loadA(T + 1, af[(T + 1) & 1]);
            if (t < 8)  readB(cur, (t + 1) / 3, (t + 1) % 3, bfr[(t + 1) & 1]);
            if (kz < 2) {
                if (t == 3) writeRow(nxt, 0, s0);
                if (t == 4) writeRow(nxt, 1, s1);
                if (t == 5) writeRow(nxt, 2, s2);
                if (t == 6) writeRow(nxt, 3, s0);
                if (t == 7) writeRow(nxt, 4, s1);
                if (t == 8) writeRow(nxt, 5, s2);
                if (t == 0) s0 = issueRow(d + kz + 1, 0);
                if (t == 1) s1 = issueRow(d + kz + 1, 1);
                if (t == 2) s2 = issueRow(d + kz + 1, 2);
                if (t == 3) s0 = issueRow(d + kz + 1, 3);
                if (t == 4) s1 = issueRow(d + kz + 1, 4);
                if (t == 5) s2 = issueRow(d + kz + 1, 5);
            }
#pragma unroll
            for (int mt = 0; mt < 4; ++mt)
#pragma unroll
                for (int nt = 0; nt < 4; ++nt)
                    acc[mt][nt] = __builtin_amdgcn_mfma_f32_16x16x32_bf16(
                        __builtin_bit_cast(bf16x8, af[T & 1][mt]),
                        __builtin_bit_cast(bf16x8, bfr[t & 1][nt]),
                        acc[mt][nt], 0, 0, 0);
        }
        if (kz < 2) __syncthreads();
    }

    const int h = h0 + row;
    if (h < DOUT) {
#pragma unroll
        for (int mt = 0; mt < 4; ++mt) {
#pragma unroll
            for (int r = 0; r < 4; ++r) {
                int oc = mt * 16 + whi * 4 + r;
                size_t ob = ((((size_t)b * OCH + oc) * DOUT + d) * DOUT + h) * DOUT;
#pragma unroll
                for (int nt = 0; nt < 4; ++nt) {
                    int ww = nt * 16 + wlo;
                    if (ww < DOUT) out[ob + ww] = acc[mt][nt][r];
                }
            }
        }
    }
}

extern "C" void kernel_launch(void* const* d_in, const int* in_sizes, int n_in,
                              void* d_out, int out_size, void* d_ws, size_t ws_size,
                              hipStream_t stream) {
    const float* x = (const float*)d_in[0];
    const float* W = (const float*)d_in[1];
    float* out = (float*)d_out;

    const size_t wre_elems = (size_t)27 * OCH * ICH;             // 55,296 ushort
    const size_t xp_elems  = (size_t)2 * DIN * DIN * DIN * ICH;  // 16,777,216 ushort
    const size_t need = (wre_elems + xp_elems) * 2 + 256;

    if (ws_size >= need) {
        unsigned short* Wre3 = (unsigned short*)d_ws;
        unsigned short* xp   = Wre3 + wre_elems;
        prep_all<<<dim3(8192 + 216), 256, 0, stream>>>(x, W, Wre3, xp);
        conv3d_mfma_pk<<<dim3(2 * DOUT * 16), 256, 0, stream>>>(Wre3, xp, out);  // 1984 = 8*248
    } else {
        conv3d_mfma_fb<<<dim3(2 * DOUT * 16), 256, 0, stream>>>(x, W, out);
    }
}